// Round 1
// baseline (368.396 us; speedup 1.0000x reference)
//
#include <hip/hip_runtime.h>

// WildcatPool2d: x[32,512,64,64] f32 -> out[32,512] f32
// out[r] = mean(top-819 of row r) + 0.7 * mean(bottom-819 of row r), rows of 4096.
// One block per row; 16 values/thread in registers; exact 3-pass radix select
// (11+11+10 bits) on order-preserving uint keys for both the 819th-largest and
// 819th-smallest, then a tie-corrected masked sum.

#define TPB 256
#define NPR 4096          // elements per row
#define KSEL 819u         // round(0.2 * 4096)
#define VPT 16            // values per thread
#define ALPHA_OVER_K (0.7f / 819.0f)
#define INV_K (1.0f / 819.0f)

__device__ __forceinline__ unsigned f2k(float f) {
    unsigned u = __float_as_uint(f);
    // positive: u | 0x80000000 ; negative: ~u   (monotone: larger float -> larger key)
    return u ^ (((unsigned)((int)u >> 31)) | 0x80000000u);
}

__device__ __forceinline__ float k2f(unsigned k) {
    unsigned u = (k & 0x80000000u) ? (k ^ 0x80000000u) : ~k;
    return __uint_as_float(u);
}

// Executed by one full wave. hist: 2048 bins; chunk[t] = sum(hist[8t..8t+7]).
// Finds bin d such that the kk-th LARGEST element (1-based, among elements in
// this histogram) falls in bin d. Writes new rank (within bin d) and d.
__device__ __forceinline__ void scan_top(const unsigned* hist, const unsigned* chunk,
                                         unsigned kk, unsigned* out_kk, unsigned* out_d) {
    const int lane = threadIdx.x & 63;
    const uint4 cv = *(const uint4*)(chunk + 4 * lane);   // lane owns chunks 4L..4L+3 (bins 32L..32L+31)
    const unsigned s = cv.x + cv.y + cv.z + cv.w;
    int S = (int)s;
    #pragma unroll
    for (int off = 1; off < 64; off <<= 1) {              // inclusive suffix scan over lanes
        int t = __shfl_down(S, off);
        if (lane + off < 64) S += t;
    }
    const unsigned Su = (unsigned)S;
    const unsigned above = Su - s;                        // count in all higher-lane chunks
    if (Su >= kk && above < kk) {                         // exactly one lane hits
        unsigned c = above;
        const unsigned ch[4] = {cv.x, cv.y, cv.z, cv.w};
        for (int q = 3; q >= 0; --q) {
            const unsigned cq = ch[q];
            if (c + cq >= kk) {
                const int bbase = (4 * lane + q) * 8;
                for (int d = 7; d >= 0; --d) {
                    const unsigned hd = hist[bbase + d];
                    if (c + hd >= kk) { *out_kk = kk - c; *out_d = (unsigned)(bbase + d); return; }
                    c += hd;
                }
                return; // unreachable
            }
            c += cq;
        }
    }
}

// Same, but for the kk-th SMALLEST element.
__device__ __forceinline__ void scan_bot(const unsigned* hist, const unsigned* chunk,
                                         unsigned kk, unsigned* out_kk, unsigned* out_d) {
    const int lane = threadIdx.x & 63;
    const uint4 cv = *(const uint4*)(chunk + 4 * lane);
    const unsigned s = cv.x + cv.y + cv.z + cv.w;
    int P = (int)s;
    #pragma unroll
    for (int off = 1; off < 64; off <<= 1) {              // inclusive prefix scan over lanes
        int t = __shfl_up(P, off);
        if (lane >= off) P += t;
    }
    const unsigned Pu = (unsigned)P;
    const unsigned below = Pu - s;
    if (Pu >= kk && below < kk) {
        unsigned c = below;
        const unsigned ch[4] = {cv.x, cv.y, cv.z, cv.w};
        for (int q = 0; q < 4; ++q) {
            const unsigned cq = ch[q];
            if (c + cq >= kk) {
                const int bbase = (4 * lane + q) * 8;
                for (int d = 0; d < 8; ++d) {
                    const unsigned hd = hist[bbase + d];
                    if (c + hd >= kk) { *out_kk = kk - c; *out_d = (unsigned)(bbase + d); return; }
                    c += hd;
                }
                return; // unreachable
            }
            c += cq;
        }
    }
}

__global__ __launch_bounds__(TPB, 4)
void wildcat_kernel(const float* __restrict__ x, float* __restrict__ out) {
    __shared__ __align__(16) unsigned hist0[2048];   // top-select histogram (pass1: shared by both)
    __shared__ __align__(16) unsigned hist1[2048];   // bottom-select histogram
    __shared__ __align__(16) unsigned chunk0[256];
    __shared__ __align__(16) unsigned chunk1[256];
    __shared__ unsigned ctl[4];                      // kk_top, digit_top, kk_bot, digit_bot
    __shared__ float    redf[8];
    __shared__ unsigned redu[8];

    const int tid = threadIdx.x;
    const int wid = tid >> 6;
    const int row = blockIdx.x;

    // ---- load 16 values/thread, coalesced float4, convert to sortable keys ----
    const float4* __restrict__ p = (const float4*)(x + (size_t)row * NPR);
    unsigned key[VPT];
    #pragma unroll
    for (int i = 0; i < 4; ++i) {
        const float4 v = p[tid + i * TPB];
        key[4*i + 0] = f2k(v.x);
        key[4*i + 1] = f2k(v.y);
        key[4*i + 2] = f2k(v.z);
        key[4*i + 3] = f2k(v.w);
    }

    // ============ pass 1: bits [31:21] (shared histogram for both selects) ============
    #pragma unroll
    for (int j = 0; j < 8; ++j) hist0[tid + j * 256] = 0u;
    __syncthreads();
    #pragma unroll
    for (int i = 0; i < VPT; ++i) atomicAdd(&hist0[key[i] >> 21], 1u);
    __syncthreads();
    {
        const uint4* h4 = (const uint4*)(hist0 + tid * 8);
        const uint4 a = h4[0], b = h4[1];
        chunk0[tid] = a.x + a.y + a.z + a.w + b.x + b.y + b.z + b.w;
    }
    __syncthreads();
    if (wid == 0)      scan_top(hist0, chunk0, KSEL, &ctl[0], &ctl[1]);
    else if (wid == 1) scan_bot(hist0, chunk0, KSEL, &ctl[2], &ctl[3]);
    __syncthreads();
    unsigned kkt = ctl[0], pt = ctl[1];
    unsigned kkb = ctl[2], pb = ctl[3];

    // ============ pass 2: bits [20:10] ============
    #pragma unroll
    for (int j = 0; j < 8; ++j) { hist0[tid + j * 256] = 0u; hist1[tid + j * 256] = 0u; }
    __syncthreads();
    #pragma unroll
    for (int i = 0; i < VPT; ++i) {
        const unsigned hi  = key[i] >> 21;
        const unsigned mid = (key[i] >> 10) & 0x7FFu;
        if (hi == pt) atomicAdd(&hist0[mid], 1u);
        if (hi == pb) atomicAdd(&hist1[mid], 1u);
    }
    __syncthreads();
    {
        const uint4* h4 = (const uint4*)(hist0 + tid * 8);
        const uint4 a = h4[0], b = h4[1];
        chunk0[tid] = a.x + a.y + a.z + a.w + b.x + b.y + b.z + b.w;
        const uint4* g4 = (const uint4*)(hist1 + tid * 8);
        const uint4 c = g4[0], d = g4[1];
        chunk1[tid] = c.x + c.y + c.z + c.w + d.x + d.y + d.z + d.w;
    }
    __syncthreads();
    if (wid == 0)      scan_top(hist0, chunk0, kkt, &ctl[0], &ctl[1]);
    else if (wid == 1) scan_bot(hist1, chunk1, kkb, &ctl[2], &ctl[3]);
    __syncthreads();
    kkt = ctl[0]; pt = (pt << 11) | ctl[1];
    kkb = ctl[2]; pb = (pb << 11) | ctl[3];

    // ============ pass 3: bits [9:0] (1024 live bins; zero all 2048 for uniform scan) ============
    #pragma unroll
    for (int j = 0; j < 8; ++j) { hist0[tid + j * 256] = 0u; hist1[tid + j * 256] = 0u; }
    __syncthreads();
    #pragma unroll
    for (int i = 0; i < VPT; ++i) {
        const unsigned hi = key[i] >> 10;
        const unsigned lo = key[i] & 0x3FFu;
        if (hi == pt) atomicAdd(&hist0[lo], 1u);
        if (hi == pb) atomicAdd(&hist1[lo], 1u);
    }
    __syncthreads();
    {
        const uint4* h4 = (const uint4*)(hist0 + tid * 8);
        const uint4 a = h4[0], b = h4[1];
        chunk0[tid] = a.x + a.y + a.z + a.w + b.x + b.y + b.z + b.w;
        const uint4* g4 = (const uint4*)(hist1 + tid * 8);
        const uint4 c = g4[0], d = g4[1];
        chunk1[tid] = c.x + c.y + c.z + c.w + d.x + d.y + d.z + d.w;
    }
    __syncthreads();
    if (wid == 0)      scan_top(hist0, chunk0, kkt, &ctl[0], &ctl[1]);
    else if (wid == 1) scan_bot(hist1, chunk1, kkb, &ctl[2], &ctl[3]);
    __syncthreads();
    const unsigned keyT = (pt << 10) | ctl[1];   // exact 819th-largest key
    const unsigned keyB = (pb << 10) | ctl[3];   // exact 819th-smallest key

    // ============ final: tie-corrected masked sums ============
    float st = 0.f, sb = 0.f;
    unsigned ct = 0u, cb = 0u;
    #pragma unroll
    for (int i = 0; i < VPT; ++i) {
        const unsigned k = key[i];
        const float v = k2f(k);
        if (k > keyT) { st += v; ct += 1u; }
        if (k < keyB) { sb += v; cb += 1u; }
    }
    #pragma unroll
    for (int off = 32; off >= 1; off >>= 1) {
        st += __shfl_down(st, off);
        sb += __shfl_down(sb, off);
        ct += (unsigned)__shfl_down((int)ct, off);
        cb += (unsigned)__shfl_down((int)cb, off);
    }
    if ((tid & 63) == 0) { redf[wid] = st; redf[4 + wid] = sb; redu[wid] = ct; redu[4 + wid] = cb; }
    __syncthreads();
    if (tid == 0) {
        float    ST = redf[0] + redf[1] + redf[2] + redf[3];
        float    SB = redf[4] + redf[5] + redf[6] + redf[7];
        unsigned CT = redu[0] + redu[1] + redu[2] + redu[3];
        unsigned CB = redu[4] + redu[5] + redu[6] + redu[7];
        ST += (float)(KSEL - CT) * k2f(keyT);   // tied copies of the kth value
        SB += (float)(KSEL - CB) * k2f(keyB);
        out[row] = ST * INV_K + ALPHA_OVER_K * SB;
    }
}

extern "C" void kernel_launch(void* const* d_in, const int* in_sizes, int n_in,
                              void* d_out, int out_size, void* d_ws, size_t ws_size,
                              hipStream_t stream) {
    const float* x = (const float*)d_in[0];
    float* out = (float*)d_out;
    wildcat_kernel<<<dim3((unsigned)out_size), dim3(TPB), 0, stream>>>(x, out);
}